// Round 9
// baseline (1002.491 us; speedup 1.0000x reference)
//
#include <hip/hip_runtime.h>

typedef __attribute__((ext_vector_type(8))) short short8;
typedef __attribute__((ext_vector_type(4))) float f32x4;

#define BATCH   131072
#define IND     300
#define MIDD    450
#define XS      328   // X LDS row stride (elems)
#define HS      488   // H LDS row stride (elems)
#define WXS     320   // W global row stride, K300-class: 640B = 64B-aligned rows
#define WHS     480   // W global row stride, K450-class: 960B = 64B-aligned rows
#define BM      32    // 32 rows/block: acc[2][NJ] -> ~115 regs -> 4 waves/SIMD
#define NTHR    512
#define NBLK    (BATCH / BM)   // 4096, exact

constexpr int SZ1 = 464 * WXS;    // [464][320] padded N450,K320 weights (row-major, bf16)
constexpr int SZ2 = 304 * WHS;    // [304][480] padded N300,K480 weights
constexpr int O_NOT1 = 0;
constexpr int O_NOT2 = SZ1;
constexpr int O_AND1 = SZ1 + SZ2;
constexpr int O_AND2 = 2 * SZ1 + SZ2;
constexpr int O_OR1  = 2 * SZ1 + 2 * SZ2;
constexpr int O_OR2  = 3 * SZ1 + 2 * SZ2;
constexpr int WS_ELEMS = 3 * SZ1 + 3 * SZ2;

constexpr int XBYTES = BM * XS * 2;           // 20992
constexpr int HBYTES = BM * HS * 2;           // 31232
constexpr int LDS_BYTES = XBYTES + HBYTES;    // 52224

__device__ __forceinline__ unsigned short f2b(float f) {
  unsigned u = __builtin_bit_cast(unsigned, f);
  u = (u + 0x7FFFu + ((u >> 16) & 1u)) >> 16;   // RNE
  return (unsigned short)u;
}
__device__ __forceinline__ float b2f(unsigned short h) {
  unsigned u = ((unsigned)h) << 16;
  return __builtin_bit_cast(float, u);
}
__device__ __forceinline__ f32x4 mfma16(short8 a, short8 b, f32x4 c) {
  asm("v_mfma_f32_16x16x32_bf16 %0, %1, %2, %0" : "+v"(c) : "v"(a), "v"(b));
  return c;
}

// ---- weight prep: f32 -> bf16, zero-padded, 64B-aligned rows; AND/OR W1 folded ----
__global__ void prep_weights(const float* __restrict__ nw1, const float* __restrict__ nw2,
                             const float* __restrict__ aw1, const float* __restrict__ aw2,
                             const float* __restrict__ ow1, const float* __restrict__ ow2,
                             unsigned short* __restrict__ ws)
{
  int idx = blockIdx.x * 256 + threadIdx.x;
  if (idx < 3 * SZ1) {
    int r = idx / SZ1, off = idx % SZ1;
    int n = off / WXS, k = off % WXS;
    float v = 0.f;
    if (n < MIDD && k < IND) {
      if (r == 0) v = nw1[n * IND + k];
      else {
        const float* s = (r == 1) ? aw1 : ow1;
        v = s[n * 2 * IND + k] + s[n * 2 * IND + IND + k];   // fold concat([x,x])
      }
    }
    int base = (r == 0) ? O_NOT1 : (r == 1) ? O_AND1 : O_OR1;
    ws[base + off] = f2b(v);
  } else if (idx < WS_ELEMS) {
    int i2 = idx - 3 * SZ1;
    int r = i2 / SZ2, off = i2 % SZ2;
    int n = off / WHS, k = off % WHS;
    float v = 0.f;
    if (n < IND && k < MIDD) {
      const float* s = (r == 0) ? nw2 : (r == 1) ? aw2 : ow2;
      v = s[n * MIDD + k];
    }
    int base = (r == 0) ? O_NOT2 : (r == 1) ? O_AND2 : O_OR2;
    ws[base + off] = f2b(v);
  }
}

// ---- one GEMM stage: OUT[32][N] = leaky(IN[32][K] @ W^T + b); MSE variant fuses vs X ----
// A from LDS (2-buf), B from L2 via 3-buffer depth-2 register pipeline. No per-K barriers.
// 16x16x32 bf16 frags: A lane: m=l&15,k=8*(l>>4)+i ; B lane: n=l&15,k=8*(l>>4)+i
// D lane: n=l&15, m=(l>>4)*4+r  (validated rounds 1-3,5,6,8)
template <int KB, int NT, int N, bool MSE>
__device__ __forceinline__ void stage(const unsigned short* __restrict__ IN, int in_stride,
                                      const unsigned short* __restrict__ Wg, int wg_stride,
                                      const float* __restrict__ bias,
                                      unsigned short* __restrict__ Hout,
                                      const unsigned short* __restrict__ XT,
                                      float& sq, int tid, int wn, int l16, int lhi)
{
  constexpr int NJ = (NT + 7) / 8;
  f32x4 acc[2][NJ];
#pragma unroll
  for (int m = 0; m < 2; m++)
#pragma unroll
    for (int j = 0; j < NJ; j++) acc[m][j] = f32x4{0.f, 0.f, 0.f, 0.f};

  const unsigned short* ap[2];
#pragma unroll
  for (int m = 0; m < 2; m++) ap[m] = IN + (m * 16 + l16) * in_stride + lhi * 8;
  const unsigned short* bp[NJ];
#pragma unroll
  for (int j = 0; j < NJ; j++) {
    int nt = wn + 8 * j;
    int row = (nt < NT ? nt : 0) * 16 + l16;      // clamp invalid tiles to row 0
    bp[j] = Wg + row * wg_stride + lhi * 8;
  }

  short8 a0[2], a1[2], b0[NJ], b1[NJ], b2[NJ];

#define LA_(buf, kk)                                                     \
  { _Pragma("unroll") for (int m = 0; m < 2; m++)                        \
      buf[m] = *(const short8*)(ap[m] + (kk) * 32); }
#define LB_(buf, kk)                                                     \
  { _Pragma("unroll") for (int j = 0; j < NJ; j++)                       \
      if (wn + 8 * j < NT) buf[j] = *(const short8*)(bp[j] + (kk) * 32); }

  LB_(b0, 0);
  LB_(b1, 1);
  LA_(a0, 0);

#pragma unroll
  for (int kb = 0; kb < KB; kb++) {
    short8* ac = (kb & 1) ? a1 : a0;
    short8* an = (kb & 1) ? a0 : a1;
    short8* bc = (kb % 3 == 0) ? b0 : (kb % 3 == 1) ? b1 : b2;
    short8* bn = ((kb + 2) % 3 == 0) ? b0 : ((kb + 2) % 3 == 1) ? b1 : b2;
    if (kb + 2 < KB) LB_(bn, kb + 2);     // depth-2 global prefetch (counted vmcnt)
    if (kb + 1 < KB) LA_(an, kb + 1);     // depth-1 LDS prefetch
#pragma unroll
    for (int j = 0; j < NJ; j++) {
      if (wn + 8 * j < NT) {
#pragma unroll
        for (int m = 0; m < 2; m++) acc[m][j] = mfma16(ac[m], bc[j], acc[m][j]);
      }
    }
  }
#undef LA_
#undef LB_

  if (!MSE) __syncthreads();   // in-place H overwrite: all waves done reading IN

#pragma unroll
  for (int j = 0; j < NJ; j++) {
    int nt = wn + 8 * j;
    if (nt >= NT) continue;
    int col = nt * 16 + l16;
    bool valid = col < N;
    float bv = valid ? bias[col] : 0.f;
#pragma unroll
    for (int m = 0; m < 2; m++) {
#pragma unroll
      for (int r = 0; r < 4; r++) {
        int row = m * 16 + lhi * 4 + r;
        float v = acc[m][j][r] + bv;
        v = v > 0.f ? v : 0.1f * v;
        if (MSE) {
          if (valid) { float d = b2f(XT[row * XS + col]) - v; sq += d * d; }
        } else {
          if (valid) Hout[row * HS + col] = f2b(v);
        }
      }
    }
  }
  if (!MSE && N == IND) {
    // zero pad cols [300,320) so the next K=320 read sees zeros
    for (int i = tid; i < BM * 20; i += NTHR) {
      int r = i / 20, c = i - r * 20;
      Hout[r * HS + IND + c] = 0;
    }
  }
}

__global__ __launch_bounds__(NTHR)
void fused(const float* __restrict__ x, const unsigned short* __restrict__ ws,
           const float* __restrict__ nb1, const float* __restrict__ nb2,
           const float* __restrict__ ab1, const float* __restrict__ ab2,
           const float* __restrict__ ob1, const float* __restrict__ ob2,
           float* __restrict__ out)
{
  extern __shared__ __align__(16) char smem[];
  unsigned short* X = (unsigned short*)smem;                 // [32][XS]
  unsigned short* H = (unsigned short*)(smem + XBYTES);      // [32][HS]
  __shared__ float wsum[8];
  int tid = threadIdx.x, wid = tid >> 6, lane = tid & 63;
  int l16 = lane & 15, lhi = lane >> 4;

  // zero X+H (K-pad columns must be 0)
  for (int i = tid; i < LDS_BYTES / 4; i += NTHR) ((unsigned*)smem)[i] = 0u;
  __syncthreads();

  int row0 = blockIdx.x * BM;
  for (int i = tid; i < BM * IND; i += NTHR) {
    int r = i / IND, c = i - r * IND;
    X[r * XS + c] = f2b(x[(size_t)(row0 + r) * IND + c]);
  }
  __syncthreads();

  float sq = 0.f;
  // NOT(NOT(x))
  stage<10, 29, MIDD, false>(X, XS, ws + O_NOT1, WXS, nb1, H, X, sq, tid, wid, l16, lhi);
  __syncthreads();
  stage<15, 19, IND,  false>(H, HS, ws + O_NOT2, WHS, nb2, H, X, sq, tid, wid, l16, lhi);
  __syncthreads();
  stage<10, 29, MIDD, false>(H, HS, ws + O_NOT1, WXS, nb1, H, X, sq, tid, wid, l16, lhi);
  __syncthreads();
  stage<15, 19, IND,  true >(H, HS, ws + O_NOT2, WHS, nb2, H, X, sq, tid, wid, l16, lhi);
  __syncthreads();
  // AND (folded W1)
  stage<10, 29, MIDD, false>(X, XS, ws + O_AND1, WXS, ab1, H, X, sq, tid, wid, l16, lhi);
  __syncthreads();
  stage<15, 19, IND,  true >(H, HS, ws + O_AND2, WHS, ab2, H, X, sq, tid, wid, l16, lhi);
  __syncthreads();
  // OR (folded W1)
  stage<10, 29, MIDD, false>(X, XS, ws + O_OR1,  WXS, ob1, H, X, sq, tid, wid, l16, lhi);
  __syncthreads();
  stage<15, 19, IND,  true >(H, HS, ws + O_OR2,  WHS, ob2, H, X, sq, tid, wid, l16, lhi);

#pragma unroll
  for (int off = 32; off > 0; off >>= 1) sq += __shfl_down(sq, off);
  if (lane == 0) wsum[wid] = sq;
  __syncthreads();
  if (tid == 0) {
    float s = 0.f;
#pragma unroll
    for (int w = 0; w < 8; w++) s += wsum[w];
    atomicAdd(out, s);
  }
}

__global__ void finalize(float* out) {
  out[0] *= (1.0f / (3.0f * (float)BATCH * (float)IND));
}

extern "C" void kernel_launch(void* const* d_in, const int* in_sizes, int n_in,
                              void* d_out, int out_size, void* d_ws, size_t ws_size,
                              hipStream_t stream) {
  const float* x   = (const float*)d_in[0];
  const float* nw1 = (const float*)d_in[1];
  const float* nb1 = (const float*)d_in[2];
  const float* nw2 = (const float*)d_in[3];
  const float* nb2 = (const float*)d_in[4];
  const float* aw1 = (const float*)d_in[5];
  const float* ab1 = (const float*)d_in[6];
  const float* aw2 = (const float*)d_in[7];
  const float* ab2 = (const float*)d_in[8];
  const float* ow1 = (const float*)d_in[9];
  const float* ob1 = (const float*)d_in[10];
  const float* ow2 = (const float*)d_in[11];
  const float* ob2 = (const float*)d_in[12];
  unsigned short* ws = (unsigned short*)d_ws;
  float* out = (float*)d_out;

  hipMemsetAsync(d_out, 0, sizeof(float), stream);

  int prep_blocks = (WS_ELEMS + 255) / 256;
  prep_weights<<<prep_blocks, 256, 0, stream>>>(nw1, nw2, aw1, aw2, ow1, ow2, ws);

  hipFuncSetAttribute((const void*)fused,
                      hipFuncAttributeMaxDynamicSharedMemorySize, LDS_BYTES);
  fused<<<NBLK, NTHR, LDS_BYTES, stream>>>(x, ws, nb1, nb2, ab1, ab2, ob1, ob2, out);

  finalize<<<1, 1, 0, stream>>>(out);
}

// Round 10
// 583.545 us; speedup vs baseline: 1.7179x; 1.7179x over previous
//
#include <hip/hip_runtime.h>

typedef __attribute__((ext_vector_type(8))) short short8;
typedef __attribute__((ext_vector_type(4))) float f32x4;

#define BATCH   131072
#define IND     300
#define MIDD    450
#define XS      328   // X LDS row stride (elems); 656B
#define HS      488   // H LDS row stride (elems); 976B
#define WXS     320   // W global row stride, K300-class: 640B = 64B-aligned rows
#define WHS     480   // W global row stride, K450-class: 960B = 64B-aligned rows
#define BM      96    // 6 m-tiles/wave: 24 MFMA per K-iter, W-traffic/CU x0.67
#define NTHR    512
#define NBLK    ((BATCH + BM - 1) / BM)   // 1366 (last block: 32 valid rows)
#define MM      (BM / 16)                 // 6 m-tiles

constexpr int SZ1 = 464 * WXS;    // [464][320] padded N450,K320 weights (row-major, bf16)
constexpr int SZ2 = 304 * WHS;    // [304][480] padded N300,K480 weights
constexpr int O_NOT1 = 0;
constexpr int O_NOT2 = SZ1;
constexpr int O_AND1 = SZ1 + SZ2;
constexpr int O_AND2 = 2 * SZ1 + SZ2;
constexpr int O_OR1  = 2 * SZ1 + 2 * SZ2;
constexpr int O_OR2  = 3 * SZ1 + 2 * SZ2;
constexpr int WS_ELEMS = 3 * SZ1 + 3 * SZ2;

constexpr int XBYTES = BM * XS * 2;           // 62976
constexpr int HBYTES = BM * HS * 2;           // 93696
constexpr int LDS_BYTES = XBYTES + HBYTES;    // 156672 <= 163840

__device__ __forceinline__ unsigned short f2b(float f) {
  unsigned u = __builtin_bit_cast(unsigned, f);
  u = (u + 0x7FFFu + ((u >> 16) & 1u)) >> 16;   // RNE
  return (unsigned short)u;
}
__device__ __forceinline__ float b2f(unsigned short h) {
  unsigned u = ((unsigned)h) << 16;
  return __builtin_bit_cast(float, u);
}
__device__ __forceinline__ f32x4 mfma16(short8 a, short8 b, f32x4 c) {
  asm("v_mfma_f32_16x16x32_bf16 %0, %1, %2, %0" : "+v"(c) : "v"(a), "v"(b));
  return c;
}

// ---- weight prep: f32 -> bf16, zero-padded, 64B-aligned rows; AND/OR W1 folded ----
__global__ void prep_weights(const float* __restrict__ nw1, const float* __restrict__ nw2,
                             const float* __restrict__ aw1, const float* __restrict__ aw2,
                             const float* __restrict__ ow1, const float* __restrict__ ow2,
                             unsigned short* __restrict__ ws)
{
  int idx = blockIdx.x * 256 + threadIdx.x;
  if (idx < 3 * SZ1) {
    int r = idx / SZ1, off = idx % SZ1;
    int n = off / WXS, k = off % WXS;
    float v = 0.f;
    if (n < MIDD && k < IND) {
      if (r == 0) v = nw1[n * IND + k];
      else {
        const float* s = (r == 1) ? aw1 : ow1;
        v = s[n * 2 * IND + k] + s[n * 2 * IND + IND + k];   // fold concat([x,x])
      }
    }
    int base = (r == 0) ? O_NOT1 : (r == 1) ? O_AND1 : O_OR1;
    ws[base + off] = f2b(v);
  } else if (idx < WS_ELEMS) {
    int i2 = idx - 3 * SZ1;
    int r = i2 / SZ2, off = i2 % SZ2;
    int n = off / WHS, k = off % WHS;
    float v = 0.f;
    if (n < IND && k < MIDD) {
      const float* s = (r == 0) ? nw2 : (r == 1) ? aw2 : ow2;
      v = s[n * MIDD + k];
    }
    int base = (r == 0) ? O_NOT2 : (r == 1) ? O_AND2 : O_OR2;
    ws[base + off] = f2b(v);
  }
}

// ---- one GEMM stage: OUT[96][N] = leaky(IN[96][K] @ W^T + b); MSE variant fuses vs X ----
// A from LDS (2-buf), B from L2 via 3-buffer depth-2 register pipeline. No per-K barriers.
// 16x16x32 bf16 frags: A lane: m=l&15,k=8*(l>>4)+i ; B lane: n=l&15,k=8*(l>>4)+i
// D lane: n=l&15, m=(l>>4)*4+r  (validated rounds 1-3,5,6,8,9)
template <int KB, int NT, int N, bool MSE>
__device__ __forceinline__ void stage(const unsigned short* __restrict__ IN, int in_stride,
                                      const unsigned short* __restrict__ Wg, int wg_stride,
                                      const float* __restrict__ bias,
                                      unsigned short* __restrict__ Hout,
                                      const unsigned short* __restrict__ XT,
                                      float& sq, int rows, int tid, int wn, int l16, int lhi)
{
  constexpr int NJ = (NT + 7) / 8;
  f32x4 acc[MM][NJ];
#pragma unroll
  for (int m = 0; m < MM; m++)
#pragma unroll
    for (int j = 0; j < NJ; j++) acc[m][j] = f32x4{0.f, 0.f, 0.f, 0.f};

  const unsigned short* ap[MM];
#pragma unroll
  for (int m = 0; m < MM; m++) ap[m] = IN + (m * 16 + l16) * in_stride + lhi * 8;
  const unsigned short* bp[NJ];
#pragma unroll
  for (int j = 0; j < NJ; j++) {
    int nt = wn + 8 * j;
    int row = (nt < NT ? nt : 0) * 16 + l16;      // clamp invalid tiles to row 0
    bp[j] = Wg + row * wg_stride + lhi * 8;
  }

  short8 a0[MM], a1[MM], b0[NJ], b1[NJ], b2[NJ];

#define LA_(buf, kk)                                                     \
  { _Pragma("unroll") for (int m = 0; m < MM; m++)                       \
      buf[m] = *(const short8*)(ap[m] + (kk) * 32); }
#define LB_(buf, kk)                                                     \
  { _Pragma("unroll") for (int j = 0; j < NJ; j++)                       \
      if (wn + 8 * j < NT) buf[j] = *(const short8*)(bp[j] + (kk) * 32); }

  LB_(b0, 0);
  LB_(b1, 1);
  LA_(a0, 0);

#pragma unroll
  for (int kb = 0; kb < KB; kb++) {
    short8* ac = (kb & 1) ? a1 : a0;
    short8* an = (kb & 1) ? a0 : a1;
    short8* bc = (kb % 3 == 0) ? b0 : (kb % 3 == 1) ? b1 : b2;
    short8* bn = ((kb + 2) % 3 == 0) ? b0 : ((kb + 2) % 3 == 1) ? b1 : b2;
    if (kb + 2 < KB) LB_(bn, kb + 2);     // depth-2 global prefetch (counted vmcnt)
    if (kb + 1 < KB) LA_(an, kb + 1);     // depth-1 LDS prefetch
    __builtin_amdgcn_s_setprio(1);
#pragma unroll
    for (int j = 0; j < NJ; j++) {
      if (wn + 8 * j < NT) {
#pragma unroll
        for (int m = 0; m < MM; m++) acc[m][j] = mfma16(ac[m], bc[j], acc[m][j]);
      }
    }
    __builtin_amdgcn_s_setprio(0);
  }
#undef LA_
#undef LB_

  if (!MSE) __syncthreads();   // in-place H overwrite: all waves done reading IN

#pragma unroll
  for (int j = 0; j < NJ; j++) {
    int nt = wn + 8 * j;
    if (nt >= NT) continue;
    int col = nt * 16 + l16;
    bool valid = col < N;
    float bv = valid ? bias[col] : 0.f;
#pragma unroll
    for (int m = 0; m < MM; m++) {
#pragma unroll
      for (int r = 0; r < 4; r++) {
        int row = m * 16 + lhi * 4 + r;
        float v = acc[m][j][r] + bv;
        v = v > 0.f ? v : 0.1f * v;
        if (MSE) {
          if (valid && row < rows) { float d = b2f(XT[row * XS + col]) - v; sq += d * d; }
        } else {
          if (valid) Hout[row * HS + col] = f2b(v);
        }
      }
    }
  }
  if (!MSE && N == IND) {
    // zero pad cols [300,320) so the next K=320 read sees zeros
    for (int i = tid; i < BM * 20; i += NTHR) {
      int r = i / 20, c = i - r * 20;
      Hout[r * HS + IND + c] = 0;
    }
  }
}

__global__ __launch_bounds__(NTHR)
void fused(const float* __restrict__ x, const unsigned short* __restrict__ ws,
           const float* __restrict__ nb1, const float* __restrict__ nb2,
           const float* __restrict__ ab1, const float* __restrict__ ab2,
           const float* __restrict__ ob1, const float* __restrict__ ob2,
           float* __restrict__ out)
{
  extern __shared__ __align__(16) char smem[];
  unsigned short* X = (unsigned short*)smem;                 // [96][XS]
  unsigned short* H = (unsigned short*)(smem + XBYTES);      // [96][HS]
  __shared__ float wsum[8];
  int tid = threadIdx.x, wid = tid >> 6, lane = tid & 63;
  int l16 = lane & 15, lhi = lane >> 4;

  // zero X+H (K-pad columns and tail rows must be 0)
  for (int i = tid; i < LDS_BYTES / 4; i += NTHR) ((unsigned*)smem)[i] = 0u;
  __syncthreads();

  int row0 = blockIdx.x * BM;
  int rows = (row0 + BM <= BATCH) ? BM : (BATCH - row0);
  for (int i = tid; i < rows * IND; i += NTHR) {
    int r = i / IND, c = i - r * IND;
    X[r * XS + c] = f2b(x[(size_t)(row0 + r) * IND + c]);
  }
  __syncthreads();

  float sq = 0.f;
  // NOT(NOT(x))
  stage<10, 29, MIDD, false>(X, XS, ws + O_NOT1, WXS, nb1, H, X, sq, rows, tid, wid, l16, lhi);
  __syncthreads();
  stage<15, 19, IND,  false>(H, HS, ws + O_NOT2, WHS, nb2, H, X, sq, rows, tid, wid, l16, lhi);
  __syncthreads();
  stage<10, 29, MIDD, false>(H, HS, ws + O_NOT1, WXS, nb1, H, X, sq, rows, tid, wid, l16, lhi);
  __syncthreads();
  stage<15, 19, IND,  true >(H, HS, ws + O_NOT2, WHS, nb2, H, X, sq, rows, tid, wid, l16, lhi);
  __syncthreads();
  // AND (folded W1)
  stage<10, 29, MIDD, false>(X, XS, ws + O_AND1, WXS, ab1, H, X, sq, rows, tid, wid, l16, lhi);
  __syncthreads();
  stage<15, 19, IND,  true >(H, HS, ws + O_AND2, WHS, ab2, H, X, sq, rows, tid, wid, l16, lhi);
  __syncthreads();
  // OR (folded W1)
  stage<10, 29, MIDD, false>(X, XS, ws + O_OR1,  WXS, ob1, H, X, sq, rows, tid, wid, l16, lhi);
  __syncthreads();
  stage<15, 19, IND,  true >(H, HS, ws + O_OR2,  WHS, ob2, H, X, sq, rows, tid, wid, l16, lhi);

#pragma unroll
  for (int off = 32; off > 0; off >>= 1) sq += __shfl_down(sq, off);
  if (lane == 0) wsum[wid] = sq;
  __syncthreads();
  if (tid == 0) {
    float s = 0.f;
#pragma unroll
    for (int w = 0; w < 8; w++) s += wsum[w];
    atomicAdd(out, s);
  }
}

__global__ void finalize(float* out) {
  out[0] *= (1.0f / (3.0f * (float)BATCH * (float)IND));
}

extern "C" void kernel_launch(void* const* d_in, const int* in_sizes, int n_in,
                              void* d_out, int out_size, void* d_ws, size_t ws_size,
                              hipStream_t stream) {
  const float* x   = (const float*)d_in[0];
  const float* nw1 = (const float*)d_in[1];
  const float* nb1 = (const float*)d_in[2];
  const float* nw2 = (const float*)d_in[3];
  const float* nb2 = (const float*)d_in[4];
  const float* aw1 = (const float*)d_in[5];
  const float* ab1 = (const float*)d_in[6];
  const float* aw2 = (const float*)d_in[7];
  const float* ab2 = (const float*)d_in[8];
  const float* ow1 = (const float*)d_in[9];
  const float* ob1 = (const float*)d_in[10];
  const float* ow2 = (const float*)d_in[11];
  const float* ob2 = (const float*)d_in[12];
  unsigned short* ws = (unsigned short*)d_ws;
  float* out = (float*)d_out;

  hipMemsetAsync(d_out, 0, sizeof(float), stream);

  int prep_blocks = (WS_ELEMS + 255) / 256;
  prep_weights<<<prep_blocks, 256, 0, stream>>>(nw1, nw2, aw1, aw2, ow1, ow2, ws);

  hipFuncSetAttribute((const void*)fused,
                      hipFuncAttributeMaxDynamicSharedMemorySize, LDS_BYTES);
  fused<<<NBLK, NTHR, LDS_BYTES, stream>>>(x, ws, nb1, nb2, ab1, ab2, ob1, ob2, out);

  finalize<<<1, 1, 0, stream>>>(out);
}